// Round 4
// baseline (1775.624 us; speedup 1.0000x reference)
//
#include <hip/hip_runtime.h>

#define D_IN 2312
#define HID  800
#define NCLS 10
#define BATCH 128
#define TSTEPS 300
#define WIN  50

#define MT 128                             // block tile rows (2 waves x 64)
#define NT 32
#define BKK 16
#define NTM 50                             // 6400/128
#define NTN 25                             // 800/32, exact
#define GEMM_BLOCKS (NTM * NTN)            // 1250 two-wave tiles
#define PASTE_BLOCKS 2048
#define BLK 128
#define TOTQ (BATCH * D_IN * (TSTEPS / 4)) // 22,195,200 float4s of X

// ---------------------------------------------------------------------------
// Fused: blocks [0,1250) = 2-wave 128x32 fp32 GEMM tiles, 8x4 outputs per
// thread. Block order mt-major: 25 consecutive blocks share one A m-tile
// (1.2 MB) + full W1 (7.4 MB) -> L2-resident (verified: FETCH 778->310 MB).
// Guards hoisted out of the hot loop (only final partial slab guarded).
// Per-output k-accumulation strictly sequential fmaf -> bit-identical P.
// X stores are PLAIN float4 (NT stores regressed: 660 MB HBM writes from
// partial-line no-allocate traffic vs 366 MB with L2 write-combining).
// blocks [1250,+2048) = grid-stride paste of X.
// ---------------------------------------------------------------------------
__global__ __launch_bounds__(BLK, 4) void fused_kernel(
    const float* __restrict__ inp,   // [B][D_IN][WIN]
    const float* __restrict__ W1,    // [HID][D_IN]
    const int*   __restrict__ idx,   // [B]
    float*       __restrict__ P,     // [6400][HID]
    float*       __restrict__ outX)  // [B][D_IN][T]
{
  __shared__ float As[BKK][MT];       // 8 KB
  __shared__ float Bs[BKK][NT + 4];   // 2.25 KB

  int t  = threadIdx.x;
  int bx = blockIdx.x;

  if (bx < GEMM_BLOCKS) {
    int mt = bx / NTN;                 // consecutive blocks share m-tile (A in L2)
    int nt = bx - mt * NTN;
    int m0 = mt * MT, n0 = nt * NT;

    // A staging: one row per thread, 16 k's (stride WIN floats, imm offsets)
    int am = t;                        // 0..127
    int r  = m0 + am;
    int bb = r / 50, ss = r - bb * 50;
    const float* aptr = inp + (size_t)bb * (D_IN * WIN) + ss;   // + k*WIN

    // B staging: 32 n x 16 k by 128 threads (4 each), coalesced along k
    int bn = t >> 4;                   // 0..7
    int bk = t & 15;                   // 0..15

    int ah = t >> 6;                   // wave id
    int l  = t & 63;
    int lm = l & 7;                    // m micro-group
    int ln = l >> 3;                   // n micro-group
    int tm = ah * 64 + lm * 8;         // 8 rows per thread
    int tn = ln * 4;                   // 4 cols per thread

    float aN[16], bN[4];
#pragma unroll
    for (int q = 0; q < 16; ++q) aN[q] = aptr[q * WIN];
#pragma unroll
    for (int p = 0; p < 4; ++p)
      bN[p] = W1[(size_t)(n0 + bn + 8 * p) * D_IN + bk];

    float acc[8][4] = {};

    for (int k0 = 0; k0 < D_IN; k0 += BKK) {   // 145 slabs, last partial
#pragma unroll
      for (int q = 0; q < 16; ++q) As[q][am] = aN[q];
#pragma unroll
      for (int p = 0; p < 4; ++p) Bs[bk][bn + 8 * p] = bN[p];
      __syncthreads();

      int kn0 = k0 + BKK;
      if (kn0 + BKK <= D_IN) {
        // next slab fully in range: guard-free prefetch (hot path, 144/145)
#pragma unroll
        for (int q = 0; q < 16; ++q) aN[q] = aptr[(kn0 + q) * WIN];
#pragma unroll
        for (int p = 0; p < 4; ++p)
          bN[p] = W1[(size_t)(n0 + bn + 8 * p) * D_IN + kn0 + bk];
      } else if (kn0 < D_IN) {
        // next slab partial: guarded, zero-fill (adds exact 0s to acc)
#pragma unroll
        for (int q = 0; q < 16; ++q) {
          int kk = kn0 + q;
          aN[q] = (kk < D_IN) ? aptr[kk * WIN] : 0.f;
        }
#pragma unroll
        for (int p = 0; p < 4; ++p) {
          int kk = kn0 + bk;
          bN[p] = (kk < D_IN) ? W1[(size_t)(n0 + bn + 8 * p) * D_IN + kk] : 0.f;
        }
      }

#pragma unroll
      for (int kk = 0; kk < BKK; ++kk) {
        float4 A0 = *(const float4*)&As[kk][tm];
        float4 A1 = *(const float4*)&As[kk][tm + 4];
        float4 B0 = *(const float4*)&Bs[kk][tn];
        float av[8] = {A0.x, A0.y, A0.z, A0.w, A1.x, A1.y, A1.z, A1.w};
        float bv[4] = {B0.x, B0.y, B0.z, B0.w};
#pragma unroll
        for (int i = 0; i < 8; ++i)
#pragma unroll
          for (int j = 0; j < 4; ++j)
            acc[i][j] += av[i] * bv[j];
      }
      __syncthreads();
    }

#pragma unroll
    for (int i = 0; i < 8; ++i) {
      int row = m0 + tm + i;
      *(float4*)&P[(size_t)row * HID + n0 + tn] =
          make_float4(acc[i][0], acc[i][1], acc[i][2], acc[i][3]);
    }
  } else {
    // ---- paste path: X = zeros with input window pasted at idx[b] ----
    int tid = (bx - GEMM_BLOCKS) * BLK + t;
    const int stride = PASTE_BLOCKS * BLK;
    for (int i = tid; i < TOTQ; i += stride) {
      int q  = i % 75;
      int rd = i / 75;
      int b  = rd / D_IN;
      int d  = rd - b * D_IN;
      int ib = idx[b];
      const float* ip = inp + (size_t)b * (D_IN * WIN) + (size_t)d * WIN;
      int t0 = q * 4;
      float v[4];
#pragma unroll
      for (int e = 0; e < 4; ++e) {
        unsigned w = (unsigned)(t0 + e - ib);
        v[e] = (w < (unsigned)WIN) ? ip[w] : 0.f;
      }
      *(float4*)&outX[(size_t)rd * TSTEPS + t0] = make_float4(v[0], v[1], v[2], v[3]);
    }
  }
}

// ---------------------------------------------------------------------------
// Recurrence v4 — single-pass. One wave per batch (latency-bound, 1 wave/CU,
// so occupancy is irrelevant -> __launch_bounds__(64,1) unlocks the full VGPR
// file and everything lives in registers). Unchanged to keep attribution clean.
// ---------------------------------------------------------------------------
__global__ __launch_bounds__(64, 1) void recur_kernel(
    const float* __restrict__ P,    // [6400][HID]
    const float* __restrict__ W2,   // [NCLS][HID]
    const float* __restrict__ b2,   // [NCLS]
    const float* __restrict__ Wc,   // [HID+4]
    const float* __restrict__ bc,   // [1]
    const float* __restrict__ b1,   // [HID]
    const int*   __restrict__ idx,  // [B]
    float*       __restrict__ out)  // [B][NCLS]
{
  __shared__ float sW2row[NCLS][832];           // 33.3 KB, row-major

  int L = threadIdx.x;
  int b = blockIdx.x;

#pragma unroll
  for (int c = 0; c < NCLS; ++c)
    for (int base = 0; base < 832; base += 64) {
      int j = base + L;
      sW2row[c][j] = (j < HID) ? W2[c * HID + j] : 0.f;
    }

  int myidx = idx[b];
  const float* Pb = P + (size_t)b * WIN * HID;

  float m[13], b1r[13], wcr[13];
  unsigned smask = 0;
#pragma unroll
  for (int rr = 0; rr < 13; ++rr) {
    int j = L + 64 * rr;
    m[rr]   = 0.f;
    b1r[rr] = (j < HID) ? b1[j] : 0.f;
    wcr[rr] = (j < HID) ? Wc[j] : 0.f;
  }

  float cm = 0.f, cs = 0.f, bgt = 1.f;
  float bc0 = bc[0];
  float wf0 = Wc[HID], wf1 = Wc[HID + 1], wf2 = Wc[HID + 2], wf3 = Wc[HID + 3];

  float h2m[10], h2s[10], sum2[10], b2r[10];
#pragma unroll
  for (int c = 0; c < NCLS; ++c) { h2m[c] = 0.f; h2s[c] = 0.f; sum2[c] = 0.f; b2r[c] = b2[c]; }

  __syncthreads();

  // prefetch P row for step 0
  float cur[13];
  {
    unsigned w0 = (unsigned)(0 - myidx);
    if (w0 < (unsigned)WIN) {
      const float* Pr = Pb + (size_t)w0 * HID;
#pragma unroll
      for (int rr = 0; rr < 13; ++rr) {
        int j = L + 64 * rr;
        cur[rr] = (j < HID) ? Pr[j] : 0.f;
      }
    } else {
#pragma unroll
      for (int rr = 0; rr < 13; ++rr) cur[rr] = 0.f;
    }
  }

  for (int step = 0; step < TSTEPS; ++step) {
    float gate = (step == 0) ? 1.f : cs;

    // unconditional prefetch of next step's P row (independent of this
    // step's chain; gating is applied at use as *gate, exact for {0,1})
    float nxt[13];
    {
      unsigned wn = (unsigned)(step + 1 - myidx);
      if (wn < (unsigned)WIN) {
        const float* Pr = Pb + (size_t)wn * HID;
#pragma unroll
        for (int rr = 0; rr < 13; ++rr) {
          int j = L + 64 * rr;
          nxt[rr] = (j < HID) ? Pr[j] : 0.f;
        }
      } else {
#pragma unroll
        for (int rr = 0; rr < 13; ++rr) nxt[rr] = 0.f;
      }
    }

    unsigned nmask = 0;
#pragma unroll
    for (int rr = 0; rr < 13; ++rr) {
      float mprev = ((smask >> rr) & 1u) ? 0.f : m[rr] * 0.1f;
      float mv = mprev + cur[rr] * gate + b1r[rr];
      m[rr] = mv;
      nmask |= (mv > 0.5f) ? (1u << rr) : 0u;
    }
    smask = nmask;

    unsigned long long ball = __ballot(smask != 0u);

    float ctrl = 0.f;
    float dot[10];
#pragma unroll
    for (int c = 0; c < NCLS; ++c) dot[c] = 0.f;

    if (ball) {
      // ctrl dot: branchless FMA over own units, all-register
      float cacc = 0.f;
#pragma unroll
      for (int rr = 0; rr < 13; ++rr) {
        float f = (float)((smask >> rr) & 1u);
        cacc = fmaf(f, wcr[rr], cacc);
      }
      cacc += __shfl_xor(cacc, 1);
      cacc += __shfl_xor(cacc, 2);
      cacc += __shfl_xor(cacc, 4);
      cacc += __shfl_xor(cacc, 8);
      cacc += __shfl_xor(cacc, 16);
      cacc += __shfl_xor(cacc, 32);
      ctrl = cacc;

      // h2 dot (same FMA + butterfly order as the proven deferred replay)
#pragma unroll
      for (int rr = 0; rr < 13; ++rr) {
        float f = (float)((smask >> rr) & 1u);
        int j = L + 64 * rr;
#pragma unroll
        for (int c = 0; c < NCLS; ++c)
          dot[c] = fmaf(f, sW2row[c][j], dot[c]);
      }
#pragma unroll
      for (int c = 0; c < NCLS; ++c) {
        float v = dot[c];
        v += __shfl_xor(v, 1);
        v += __shfl_xor(v, 2);
        v += __shfl_xor(v, 4);
        v += __shfl_xor(v, 8);
        v += __shfl_xor(v, 16);
        v += __shfl_xor(v, 32);
        dot[c] = v;
      }
    }

    // ctrl neuron + budget (uses prev-step cs, then updates it)
    bgt += (cs == 1.f) ? 1.f : 0.f;
    float fq = wf0;
    if ((step & 1) == 0)   fq += wf1;
    if (step % 10 == 0)    fq += wf2;
    if (step % 100 == 0)   fq += wf3;
    float cv = (cs != 0.f ? 0.f : cm * 0.1f) + ctrl + fq + bc0;
    cm = cv;
    cs = (cv > 0.5f) ? 1.f : 0.f;

    // h2 membrane update every step (dot==0 on silent steps)
#pragma unroll
    for (int c = 0; c < NCLS; ++c) {
      float v = (h2s[c] != 0.f ? 0.f : h2m[c] * 0.1f) + dot[c] + b2r[c];
      h2m[c] = v;
      h2s[c] = (v > 0.5f) ? 1.f : 0.f;
      sum2[c] += h2s[c];
    }

#pragma unroll
    for (int rr = 0; rr < 13; ++rr) cur[rr] = nxt[rr];
  }

  if (L == 0) {
#pragma unroll
    for (int c = 0; c < NCLS; ++c) out[b * NCLS + c] = sum2[c] / bgt;
  }
}

// ---------------------------------------------------------------------------
extern "C" void kernel_launch(void* const* d_in, const int* in_sizes, int n_in,
                              void* d_out, int out_size, void* d_ws, size_t ws_size,
                              hipStream_t stream) {
  const float* inp = (const float*)d_in[0];
  const int*   idx = (const int*)d_in[2];
  const float* W1  = (const float*)d_in[3];
  const float* b1  = (const float*)d_in[4];
  const float* W2  = (const float*)d_in[5];
  const float* b2  = (const float*)d_in[6];
  const float* Wc  = (const float*)d_in[7];
  const float* bc  = (const float*)d_in[8];

  float* out = (float*)d_out;   // [0,1280): rate ; then X
  float* P   = (float*)d_ws;    // [6400][800] fp32 = 20.48 MB

  fused_kernel<<<GEMM_BLOCKS + PASTE_BLOCKS, BLK, 0, stream>>>(
      inp, W1, idx, P, out + BATCH * NCLS);

  recur_kernel<<<BATCH, 64, 0, stream>>>(P, W2, b2, Wc, bc, b1, idx, out);
}

// Round 6
// 1101.631 us; speedup vs baseline: 1.6118x; 1.6118x over previous
//
#include <hip/hip_runtime.h>

#define D_IN 2312
#define HID  800
#define NCLS 10
#define BATCH 128
#define TSTEPS 300
#define WIN  50

#define MT 64                              // block tile rows (2 waves x 32)
#define NT 32
#define BKK 16
#define NTM 100                            // 6400/64
#define NTN 25                             // 800/32, exact
#define GEMM_BLOCKS (NTM * NTN)            // 2500 two-wave tiles
#define PASTE_BLOCKS 2048
#define BLK 128
#define TOTQ (BATCH * D_IN * (TSTEPS / 4)) // 22,195,200 float4s of X

// ---------------------------------------------------------------------------
// Fused GEMM+paste — EXACT round-1 structure (proven 393 us, VGPR 48, no
// spill; round-2's 8x4 rewrite spilled at VGPR 64 -> +330 MB scratch writes
// and 2.7x regression). One surgical change vs round 1: prefetch guards
// hoisted out of the hot loop (full-slab fast path for 143/145 slabs).
// Per-output k-accumulation remains strictly sequential fmaf -> bit-identical P.
// ---------------------------------------------------------------------------
__global__ __launch_bounds__(BLK) void fused_kernel(
    const float* __restrict__ inp,   // [B][D_IN][WIN]
    const float* __restrict__ W1,    // [HID][D_IN]
    const int*   __restrict__ idx,   // [B]
    float*       __restrict__ P,     // [6400][HID]
    float*       __restrict__ outX)  // [B][D_IN][T]
{
  __shared__ float As[BKK][MT];       // 4 KB
  __shared__ float Bs[BKK][NT + 4];   // 2.25 KB

  int t  = threadIdx.x;
  int bx = blockIdx.x;

  if (bx < GEMM_BLOCKS) {
    int nt = bx / NTM;                 // consecutive blocks share n-tile (L2)
    int mt = bx - nt * NTM;
    int m0 = mt * MT, n0 = nt * NT;

    // A staging: 64 rows x 16 k staged by 128 threads (8 k's each),
    // coalesced along m (s-contiguous)
    int am = t & 63;
    int ah = t >> 6;                   // 0..1 -> k-half (== wave id)
    int r  = m0 + am;
    int bb = r / 50, ss = r - bb * 50;
    const float* aptr = inp + (size_t)bb * (D_IN * WIN) + ss;   // + k*WIN

    // B staging: 32 n x 16 k by 128 threads (4 each), coalesced along k
    int bn = t >> 4;                   // 0..7
    int bk = t & 15;                   // 0..15

    int l  = t & 63;
    int lm = l & 7;                    // m micro-group
    int ln = l >> 3;                   // n micro-group
    int tm = ah * 32 + lm * 4;         // wave ah owns rows [ah*32, ah*32+32)
    int tn = ln * 4;

    float aN[8], bN[4];
#pragma unroll
    for (int q = 0; q < 8; ++q) aN[q] = aptr[(ah * 8 + q) * WIN];
#pragma unroll
    for (int p = 0; p < 4; ++p)
      bN[p] = W1[(size_t)(n0 + bn + 8 * p) * D_IN + bk];

    float acc[4][4] = {};

    for (int k0 = 0; k0 < D_IN; k0 += BKK) {   // 145 slabs, last partial
#pragma unroll
      for (int q = 0; q < 8; ++q) As[ah * 8 + q][am] = aN[q];
#pragma unroll
      for (int p = 0; p < 4; ++p) Bs[bk][bn + 8 * p] = bN[p];
      __syncthreads();

      int kn0 = k0 + BKK;
      if (kn0 + BKK <= D_IN) {
        // next slab fully in range: guard-free prefetch (hot path, 143/145)
#pragma unroll
        for (int q = 0; q < 8; ++q) aN[q] = aptr[(kn0 + ah * 8 + q) * WIN];
#pragma unroll
        for (int p = 0; p < 4; ++p)
          bN[p] = W1[(size_t)(n0 + bn + 8 * p) * D_IN + kn0 + bk];
      } else if (kn0 < D_IN) {
        // next slab partial: guarded, zero-fill (adds exact 0s to acc)
#pragma unroll
        for (int q = 0; q < 8; ++q) {
          int kk = kn0 + ah * 8 + q;
          aN[q] = (kk < D_IN) ? aptr[kk * WIN] : 0.f;
        }
#pragma unroll
        for (int p = 0; p < 4; ++p) {
          int kk = kn0 + bk;
          bN[p] = (kk < D_IN) ? W1[(size_t)(n0 + bn + 8 * p) * D_IN + kk] : 0.f;
        }
      }

#pragma unroll
      for (int kk = 0; kk < BKK; ++kk) {
        float4 A0 = *(const float4*)&As[kk][tm];
        float4 B0 = *(const float4*)&Bs[kk][tn];
        float av[4] = {A0.x, A0.y, A0.z, A0.w};
        float bv[4] = {B0.x, B0.y, B0.z, B0.w};
#pragma unroll
        for (int i = 0; i < 4; ++i)
#pragma unroll
          for (int j = 0; j < 4; ++j)
            acc[i][j] += av[i] * bv[j];
      }
      __syncthreads();
    }

#pragma unroll
    for (int i = 0; i < 4; ++i) {
      int row = m0 + tm + i;
      *(float4*)&P[(size_t)row * HID + n0 + tn] =
          make_float4(acc[i][0], acc[i][1], acc[i][2], acc[i][3]);
    }
  } else {
    // ---- paste path: X = zeros with input window pasted at idx[b] ----
    int tid = (bx - GEMM_BLOCKS) * BLK + t;
    const int stride = PASTE_BLOCKS * BLK;
    for (int i = tid; i < TOTQ; i += stride) {
      int q  = i % 75;
      int rd = i / 75;
      int b  = rd / D_IN;
      int d  = rd - b * D_IN;
      int ib = idx[b];
      const float* ip = inp + (size_t)b * (D_IN * WIN) + (size_t)d * WIN;
      int t0 = q * 4;
      float v[4];
#pragma unroll
      for (int e = 0; e < 4; ++e) {
        unsigned w = (unsigned)(t0 + e - ib);
        v[e] = (w < (unsigned)WIN) ? ip[w] : 0.f;
      }
      *(float4*)&outX[(size_t)rd * TSTEPS + t0] = make_float4(v[0], v[1], v[2], v[3]);
    }
  }
}

// ---------------------------------------------------------------------------
// DPP full-wave sum: VALU-speed cross-lane (no LDS pipe, unlike __shfl_xor's
// ds_swizzle lowering whose 6-deep ~100cy chains dominated recur's serial
// step). dpp_ctrl must be an integer-constant -> template parameter.
// row_shr 1/2/4/8 accumulate row sums into lane 15 of each 16-row;
// row_bcast15 folds r0->r1 (lane31) and r2->r3 (lane63); row_bcast31 folds
// lane31 into rows 2-3 -> lane 63 holds the wave total. bound_ctrl=1
// zero-fills invalid lanes (exact +0.0). Broadcast via readlane 63.
// Sum ORDER differs from the old butterfly — safe: outputs are spike counts
// / integer budget; threshold decisions have margin >> 1 ulp.
// ---------------------------------------------------------------------------
template <int CTRL>
__device__ __forceinline__ float dpp_add(float s) {
  return s + __int_as_float(__builtin_amdgcn_update_dpp(
      0, __float_as_int(s), CTRL, 0xf, 0xf, true));
}
__device__ __forceinline__ float wave_sum(float s) {
  s = dpp_add<0x111>(s);   // row_shr:1
  s = dpp_add<0x112>(s);   // row_shr:2
  s = dpp_add<0x114>(s);   // row_shr:4
  s = dpp_add<0x118>(s);   // row_shr:8   -> lane15 of each row = row sum
  s = dpp_add<0x142>(s);   // row_bcast:15 -> lane31 = r0+r1, lane63 = r2+r3
  s = dpp_add<0x143>(s);   // row_bcast:31 -> lane63 = total
  return __int_as_float(__builtin_amdgcn_readlane(__float_as_int(s), 63));
}

// ---------------------------------------------------------------------------
// Recurrence v5 — v4 single-pass structure with both cross-lane reductions
// (ctrl dot + 10 h2 dots) switched from __shfl_xor butterflies (66 LDS-pipe
// swizzles/step, serial latency ~1000cy/step) to DPP wave_sum (66 VALU adds).
// Everything else unchanged.
// ---------------------------------------------------------------------------
__global__ __launch_bounds__(64, 1) void recur_kernel(
    const float* __restrict__ P,    // [6400][HID]
    const float* __restrict__ W2,   // [NCLS][HID]
    const float* __restrict__ b2,   // [NCLS]
    const float* __restrict__ Wc,   // [HID+4]
    const float* __restrict__ bc,   // [1]
    const float* __restrict__ b1,   // [HID]
    const int*   __restrict__ idx,  // [B]
    float*       __restrict__ out)  // [B][NCLS]
{
  __shared__ float sW2row[NCLS][832];           // 33.3 KB, row-major

  int L = threadIdx.x;
  int b = blockIdx.x;

#pragma unroll
  for (int c = 0; c < NCLS; ++c)
    for (int base = 0; base < 832; base += 64) {
      int j = base + L;
      sW2row[c][j] = (j < HID) ? W2[c * HID + j] : 0.f;
    }

  int myidx = idx[b];
  const float* Pb = P + (size_t)b * WIN * HID;

  float m[13], b1r[13], wcr[13];
  unsigned smask = 0;
#pragma unroll
  for (int rr = 0; rr < 13; ++rr) {
    int j = L + 64 * rr;
    m[rr]   = 0.f;
    b1r[rr] = (j < HID) ? b1[j] : 0.f;
    wcr[rr] = (j < HID) ? Wc[j] : 0.f;
  }

  float cm = 0.f, cs = 0.f, bgt = 1.f;
  float bc0 = bc[0];
  float wf0 = Wc[HID], wf1 = Wc[HID + 1], wf2 = Wc[HID + 2], wf3 = Wc[HID + 3];

  float h2m[10], h2s[10], sum2[10], b2r[10];
#pragma unroll
  for (int c = 0; c < NCLS; ++c) { h2m[c] = 0.f; h2s[c] = 0.f; sum2[c] = 0.f; b2r[c] = b2[c]; }

  __syncthreads();

  // prefetch P row for step 0
  float cur[13];
  {
    unsigned w0 = (unsigned)(0 - myidx);
    if (w0 < (unsigned)WIN) {
      const float* Pr = Pb + (size_t)w0 * HID;
#pragma unroll
      for (int rr = 0; rr < 13; ++rr) {
        int j = L + 64 * rr;
        cur[rr] = (j < HID) ? Pr[j] : 0.f;
      }
    } else {
#pragma unroll
      for (int rr = 0; rr < 13; ++rr) cur[rr] = 0.f;
    }
  }

  for (int step = 0; step < TSTEPS; ++step) {
    float gate = (step == 0) ? 1.f : cs;

    // unconditional prefetch of next step's P row (independent of this
    // step's chain; gating is applied at use as *gate, exact for {0,1})
    float nxt[13];
    {
      unsigned wn = (unsigned)(step + 1 - myidx);
      if (wn < (unsigned)WIN) {
        const float* Pr = Pb + (size_t)wn * HID;
#pragma unroll
        for (int rr = 0; rr < 13; ++rr) {
          int j = L + 64 * rr;
          nxt[rr] = (j < HID) ? Pr[j] : 0.f;
        }
      } else {
#pragma unroll
        for (int rr = 0; rr < 13; ++rr) nxt[rr] = 0.f;
      }
    }

    unsigned nmask = 0;
#pragma unroll
    for (int rr = 0; rr < 13; ++rr) {
      float mprev = ((smask >> rr) & 1u) ? 0.f : m[rr] * 0.1f;
      float mv = mprev + cur[rr] * gate + b1r[rr];
      m[rr] = mv;
      nmask |= (mv > 0.5f) ? (1u << rr) : 0u;
    }
    smask = nmask;

    unsigned long long ball = __ballot(smask != 0u);

    float ctrl = 0.f;
    float dot[10];
#pragma unroll
    for (int c = 0; c < NCLS; ++c) dot[c] = 0.f;

    if (ball) {
      // ctrl dot: branchless FMA over own units, DPP wave reduce
      float cacc = 0.f;
#pragma unroll
      for (int rr = 0; rr < 13; ++rr) {
        float f = (float)((smask >> rr) & 1u);
        cacc = fmaf(f, wcr[rr], cacc);
      }
      ctrl = wave_sum(cacc);

      // h2 dots: per-lane partials over own 13 units, DPP wave reduce x10
#pragma unroll
      for (int rr = 0; rr < 13; ++rr) {
        float f = (float)((smask >> rr) & 1u);
        int j = L + 64 * rr;
#pragma unroll
        for (int c = 0; c < NCLS; ++c)
          dot[c] = fmaf(f, sW2row[c][j], dot[c]);
      }
#pragma unroll
      for (int c = 0; c < NCLS; ++c) dot[c] = wave_sum(dot[c]);
    }

    // ctrl neuron + budget (uses prev-step cs, then updates it)
    bgt += (cs == 1.f) ? 1.f : 0.f;
    float fq = wf0;
    if ((step & 1) == 0)   fq += wf1;
    if (step % 10 == 0)    fq += wf2;
    if (step % 100 == 0)   fq += wf3;
    float cv = (cs != 0.f ? 0.f : cm * 0.1f) + ctrl + fq + bc0;
    cm = cv;
    cs = (cv > 0.5f) ? 1.f : 0.f;

    // h2 membrane update every step (dot==0 on silent steps)
#pragma unroll
    for (int c = 0; c < NCLS; ++c) {
      float v = (h2s[c] != 0.f ? 0.f : h2m[c] * 0.1f) + dot[c] + b2r[c];
      h2m[c] = v;
      h2s[c] = (v > 0.5f) ? 1.f : 0.f;
      sum2[c] += h2s[c];
    }

#pragma unroll
    for (int rr = 0; rr < 13; ++rr) cur[rr] = nxt[rr];
  }

  if (L == 0) {
#pragma unroll
    for (int c = 0; c < NCLS; ++c) out[b * NCLS + c] = sum2[c] / bgt;
  }
}

// ---------------------------------------------------------------------------
extern "C" void kernel_launch(void* const* d_in, const int* in_sizes, int n_in,
                              void* d_out, int out_size, void* d_ws, size_t ws_size,
                              hipStream_t stream) {
  const float* inp = (const float*)d_in[0];
  const int*   idx = (const int*)d_in[2];
  const float* W1  = (const float*)d_in[3];
  const float* b1  = (const float*)d_in[4];
  const float* W2  = (const float*)d_in[5];
  const float* b2  = (const float*)d_in[6];
  const float* Wc  = (const float*)d_in[7];
  const float* bc  = (const float*)d_in[8];

  float* out = (float*)d_out;   // [0,1280): rate ; then X
  float* P   = (float*)d_ws;    // [6400][800] fp32 = 20.48 MB

  fused_kernel<<<GEMM_BLOCKS + PASTE_BLOCKS, BLK, 0, stream>>>(
      inp, W1, idx, P, out + BATCH * NCLS);

  recur_kernel<<<BATCH, 64, 0, stream>>>(P, W2, b2, Wc, bc, b1, idx, out);
}

// Round 7
// 1060.570 us; speedup vs baseline: 1.6742x; 1.0387x over previous
//
#include <hip/hip_runtime.h>

#define D_IN 2312
#define HID  800
#define NCLS 10
#define BATCH 128
#define TSTEPS 300
#define WIN  50

#define MT 64                              // block tile rows (2 waves x 32)
#define NT 32
#define BKK 16
#define NTM 100                            // 6400/64
#define NTN 25                             // 800/32, exact
#define GEMM_BLOCKS (NTM * NTN)            // 2500 two-wave tiles
#define PASTE_BLOCKS 2048
#define BLK 128
#define TOTQ (BATCH * D_IN * (TSTEPS / 4)) // 22,195,200 float4s of X

// ---------------------------------------------------------------------------
// Fused GEMM+paste — round-1 structure (proven 48 VGPR, no spill) with
// mt-MAJOR block order: 25 consecutive blocks share one 64-row A m-tile
// (0.6 MB) and together span all of W1 (7.4 MB, L2/L3-resident) -> A fetched
// ~once. (Round 3 proved the ordering: FETCH 778->345 MB; its regression was
// the 8x4 spill, not the ordering.) Per-output k-accumulation strictly
// sequential fmaf -> bit-identical P.
// ---------------------------------------------------------------------------
__global__ __launch_bounds__(BLK) void fused_kernel(
    const float* __restrict__ inp,   // [B][D_IN][WIN]
    const float* __restrict__ W1,    // [HID][D_IN]
    const int*   __restrict__ idx,   // [B]
    float*       __restrict__ P,     // [6400][HID]
    float*       __restrict__ outX)  // [B][D_IN][T]
{
  __shared__ float As[BKK][MT];       // 4 KB
  __shared__ float Bs[BKK][NT + 4];   // 2.25 KB

  int t  = threadIdx.x;
  int bx = blockIdx.x;

  if (bx < GEMM_BLOCKS) {
    int mt = bx / NTN;                 // 25 consecutive blocks share m-tile (A in L2)
    int nt = bx - mt * NTN;
    int m0 = mt * MT, n0 = nt * NT;

    // A staging: 64 rows x 16 k staged by 128 threads (8 k's each),
    // coalesced along m (s-contiguous)
    int am = t & 63;
    int ah = t >> 6;                   // 0..1 -> k-half (== wave id)
    int r  = m0 + am;
    int bb = r / 50, ss = r - bb * 50;
    const float* aptr = inp + (size_t)bb * (D_IN * WIN) + ss;   // + k*WIN

    // B staging: 32 n x 16 k by 128 threads (4 each), coalesced along k
    int bn = t >> 4;                   // 0..7
    int bk = t & 15;                   // 0..15

    int l  = t & 63;
    int lm = l & 7;                    // m micro-group
    int ln = l >> 3;                   // n micro-group
    int tm = ah * 32 + lm * 4;         // wave ah owns rows [ah*32, ah*32+32)
    int tn = ln * 4;

    float aN[8], bN[4];
#pragma unroll
    for (int q = 0; q < 8; ++q) aN[q] = aptr[(ah * 8 + q) * WIN];
#pragma unroll
    for (int p = 0; p < 4; ++p)
      bN[p] = W1[(size_t)(n0 + bn + 8 * p) * D_IN + bk];

    float acc[4][4] = {};

    for (int k0 = 0; k0 < D_IN; k0 += BKK) {   // 145 slabs, last partial
#pragma unroll
      for (int q = 0; q < 8; ++q) As[ah * 8 + q][am] = aN[q];
#pragma unroll
      for (int p = 0; p < 4; ++p) Bs[bk][bn + 8 * p] = bN[p];
      __syncthreads();

      int kn0 = k0 + BKK;
      if (kn0 + BKK <= D_IN) {
        // next slab fully in range: guard-free prefetch (hot path, 143/145)
#pragma unroll
        for (int q = 0; q < 8; ++q) aN[q] = aptr[(kn0 + ah * 8 + q) * WIN];
#pragma unroll
        for (int p = 0; p < 4; ++p)
          bN[p] = W1[(size_t)(n0 + bn + 8 * p) * D_IN + kn0 + bk];
      } else if (kn0 < D_IN) {
        // next slab partial: guarded, zero-fill (adds exact 0s to acc)
#pragma unroll
        for (int q = 0; q < 8; ++q) {
          int kk = kn0 + ah * 8 + q;
          aN[q] = (kk < D_IN) ? aptr[kk * WIN] : 0.f;
        }
#pragma unroll
        for (int p = 0; p < 4; ++p) {
          int kk = kn0 + bk;
          bN[p] = (kk < D_IN) ? W1[(size_t)(n0 + bn + 8 * p) * D_IN + kk] : 0.f;
        }
      }

#pragma unroll
      for (int kk = 0; kk < BKK; ++kk) {
        float4 A0 = *(const float4*)&As[kk][tm];
        float4 B0 = *(const float4*)&Bs[kk][tn];
        float av[4] = {A0.x, A0.y, A0.z, A0.w};
        float bv[4] = {B0.x, B0.y, B0.z, B0.w};
#pragma unroll
        for (int i = 0; i < 4; ++i)
#pragma unroll
          for (int j = 0; j < 4; ++j)
            acc[i][j] += av[i] * bv[j];
      }
      __syncthreads();
    }

#pragma unroll
    for (int i = 0; i < 4; ++i) {
      int row = m0 + tm + i;
      *(float4*)&P[(size_t)row * HID + n0 + tn] =
          make_float4(acc[i][0], acc[i][1], acc[i][2], acc[i][3]);
    }
  } else {
    // ---- paste path: X = zeros with input window pasted at idx[b] ----
    int tid = (bx - GEMM_BLOCKS) * BLK + t;
    const int stride = PASTE_BLOCKS * BLK;
    for (int i = tid; i < TOTQ; i += stride) {
      int q  = i % 75;
      int rd = i / 75;
      int b  = rd / D_IN;
      int d  = rd - b * D_IN;
      int ib = idx[b];
      const float* ip = inp + (size_t)b * (D_IN * WIN) + (size_t)d * WIN;
      int t0 = q * 4;
      float v[4];
#pragma unroll
      for (int e = 0; e < 4; ++e) {
        unsigned w = (unsigned)(t0 + e - ib);
        v[e] = (w < (unsigned)WIN) ? ip[w] : 0.f;
      }
      *(float4*)&outX[(size_t)rd * TSTEPS + t0] = make_float4(v[0], v[1], v[2], v[3]);
    }
  }
}

// ---------------------------------------------------------------------------
// DPP full-wave sum (proven round 6): VALU-speed cross-lane, no LDS pipe.
// ---------------------------------------------------------------------------
template <int CTRL>
__device__ __forceinline__ float dpp_add(float s) {
  return s + __int_as_float(__builtin_amdgcn_update_dpp(
      0, __float_as_int(s), CTRL, 0xf, 0xf, true));
}
__device__ __forceinline__ float wave_sum(float s) {
  s = dpp_add<0x111>(s);   // row_shr:1
  s = dpp_add<0x112>(s);   // row_shr:2
  s = dpp_add<0x114>(s);   // row_shr:4
  s = dpp_add<0x118>(s);   // row_shr:8   -> lane15 of each row = row sum
  s = dpp_add<0x142>(s);   // row_bcast:15 -> lane31 = r0+r1, lane63 = r2+r3
  s = dpp_add<0x143>(s);   // row_bcast:31 -> lane63 = total
  return __int_as_float(__builtin_amdgcn_readlane(__float_as_int(s), 63));
}

// ---------------------------------------------------------------------------
// Recurrence v6 — v5 structure with W2 moved from LDS into REGISTERS.
// The 130 sW2row ds_reads per spike-step had loop-invariant addresses and
// constant values; the compiler can't hoist them across the 300-step loop.
// w2r[10][13] (+130 VGPR, total ~260 of the 512 available at 1 wave/SIMD)
// removes all LDS traffic + lgkmcnt stalls from the serial loop. Same
// values -> same FP -> identical output. LDS array + staging + syncthreads
// dropped entirely (single-wave block).
// ---------------------------------------------------------------------------
__global__ __launch_bounds__(64, 1) void recur_kernel(
    const float* __restrict__ P,    // [6400][HID]
    const float* __restrict__ W2,   // [NCLS][HID]
    const float* __restrict__ b2,   // [NCLS]
    const float* __restrict__ Wc,   // [HID+4]
    const float* __restrict__ bc,   // [1]
    const float* __restrict__ b1,   // [HID]
    const int*   __restrict__ idx,  // [B]
    float*       __restrict__ out)  // [B][NCLS]
{
  int L = threadIdx.x;
  int b = blockIdx.x;

  int myidx = idx[b];
  const float* Pb = P + (size_t)b * WIN * HID;

  float m[13], b1r[13], wcr[13];
  float w2r[NCLS][13];
  unsigned smask = 0;
#pragma unroll
  for (int rr = 0; rr < 13; ++rr) {
    int j = L + 64 * rr;
    bool ok = (j < HID);
    m[rr]   = 0.f;
    b1r[rr] = ok ? b1[j] : 0.f;
    wcr[rr] = ok ? Wc[j] : 0.f;
#pragma unroll
    for (int c = 0; c < NCLS; ++c)
      w2r[c][rr] = ok ? W2[c * HID + j] : 0.f;
  }

  float cm = 0.f, cs = 0.f, bgt = 1.f;
  float bc0 = bc[0];
  float wf0 = Wc[HID], wf1 = Wc[HID + 1], wf2 = Wc[HID + 2], wf3 = Wc[HID + 3];

  float h2m[10], h2s[10], sum2[10], b2r[10];
#pragma unroll
  for (int c = 0; c < NCLS; ++c) { h2m[c] = 0.f; h2s[c] = 0.f; sum2[c] = 0.f; b2r[c] = b2[c]; }

  // prefetch P row for step 0
  float cur[13];
  {
    unsigned w0 = (unsigned)(0 - myidx);
    if (w0 < (unsigned)WIN) {
      const float* Pr = Pb + (size_t)w0 * HID;
#pragma unroll
      for (int rr = 0; rr < 13; ++rr) {
        int j = L + 64 * rr;
        cur[rr] = (j < HID) ? Pr[j] : 0.f;
      }
    } else {
#pragma unroll
      for (int rr = 0; rr < 13; ++rr) cur[rr] = 0.f;
    }
  }

  for (int step = 0; step < TSTEPS; ++step) {
    float gate = (step == 0) ? 1.f : cs;

    // unconditional prefetch of next step's P row (independent of this
    // step's chain; gating is applied at use as *gate, exact for {0,1})
    float nxt[13];
    {
      unsigned wn = (unsigned)(step + 1 - myidx);
      if (wn < (unsigned)WIN) {
        const float* Pr = Pb + (size_t)wn * HID;
#pragma unroll
        for (int rr = 0; rr < 13; ++rr) {
          int j = L + 64 * rr;
          nxt[rr] = (j < HID) ? Pr[j] : 0.f;
        }
      } else {
#pragma unroll
        for (int rr = 0; rr < 13; ++rr) nxt[rr] = 0.f;
      }
    }

    unsigned nmask = 0;
#pragma unroll
    for (int rr = 0; rr < 13; ++rr) {
      float mprev = ((smask >> rr) & 1u) ? 0.f : m[rr] * 0.1f;
      float mv = mprev + cur[rr] * gate + b1r[rr];
      m[rr] = mv;
      nmask |= (mv > 0.5f) ? (1u << rr) : 0u;
    }
    smask = nmask;

    unsigned long long ball = __ballot(smask != 0u);

    float ctrl = 0.f;
    float dot[10];
#pragma unroll
    for (int c = 0; c < NCLS; ++c) dot[c] = 0.f;

    if (ball) {
      // ctrl dot: branchless FMA over own units, DPP wave reduce
      float cacc = 0.f;
#pragma unroll
      for (int rr = 0; rr < 13; ++rr) {
        float f = (float)((smask >> rr) & 1u);
        cacc = fmaf(f, wcr[rr], cacc);
      }
      ctrl = wave_sum(cacc);

      // h2 dots: per-lane partials over own 13 units (all-register), then
      // DPP wave reduce x10
#pragma unroll
      for (int rr = 0; rr < 13; ++rr) {
        float f = (float)((smask >> rr) & 1u);
#pragma unroll
        for (int c = 0; c < NCLS; ++c)
          dot[c] = fmaf(f, w2r[c][rr], dot[c]);
      }
#pragma unroll
      for (int c = 0; c < NCLS; ++c) dot[c] = wave_sum(dot[c]);
    }

    // ctrl neuron + budget (uses prev-step cs, then updates it)
    bgt += (cs == 1.f) ? 1.f : 0.f;
    float fq = wf0;
    if ((step & 1) == 0)   fq += wf1;
    if (step % 10 == 0)    fq += wf2;
    if (step % 100 == 0)   fq += wf3;
    float cv = (cs != 0.f ? 0.f : cm * 0.1f) + ctrl + fq + bc0;
    cm = cv;
    cs = (cv > 0.5f) ? 1.f : 0.f;

    // h2 membrane update every step (dot==0 on silent steps)
#pragma unroll
    for (int c = 0; c < NCLS; ++c) {
      float v = (h2s[c] != 0.f ? 0.f : h2m[c] * 0.1f) + dot[c] + b2r[c];
      h2m[c] = v;
      h2s[c] = (v > 0.5f) ? 1.f : 0.f;
      sum2[c] += h2s[c];
    }

#pragma unroll
    for (int rr = 0; rr < 13; ++rr) cur[rr] = nxt[rr];
  }

  if (L == 0) {
#pragma unroll
    for (int c = 0; c < NCLS; ++c) out[b * NCLS + c] = sum2[c] / bgt;
  }
}

// ---------------------------------------------------------------------------
extern "C" void kernel_launch(void* const* d_in, const int* in_sizes, int n_in,
                              void* d_out, int out_size, void* d_ws, size_t ws_size,
                              hipStream_t stream) {
  const float* inp = (const float*)d_in[0];
  const int*   idx = (const int*)d_in[2];
  const float* W1  = (const float*)d_in[3];
  const float* b1  = (const float*)d_in[4];
  const float* W2  = (const float*)d_in[5];
  const float* b2  = (const float*)d_in[6];
  const float* Wc  = (const float*)d_in[7];
  const float* bc  = (const float*)d_in[8];

  float* out = (float*)d_out;   // [0,1280): rate ; then X
  float* P   = (float*)d_ws;    // [6400][800] fp32 = 20.48 MB

  fused_kernel<<<GEMM_BLOCKS + PASTE_BLOCKS, BLK, 0, stream>>>(
      inp, W1, idx, P, out + BATCH * NCLS);

  recur_kernel<<<BATCH, 64, 0, stream>>>(P, W2, b2, Wc, bc, b1, idx, out);
}